// Round 1
// baseline (556.312 us; speedup 1.0000x reference)
//
#include <hip/hip_runtime.h>
#include <stdint.h>
#include <math.h>

#define HID 64
#define PI_F 3.14159262358979330f

// Monotonic float <-> uint mapping so atomicMax(uint) implements float max.
__device__ __forceinline__ unsigned fmap(float f) {
    unsigned u = __float_as_uint(f);
    return (u & 0x80000000u) ? ~u : (u | 0x80000000u);
}
__device__ __forceinline__ float funmap(unsigned u) {
    unsigned v = (u & 0x80000000u) ? (u ^ 0x80000000u) : ~u;
    return __uint_as_float(v);
}

__global__ void init_nodes(unsigned* __restrict__ mmax, float* __restrict__ denom, int n) {
    int i = blockIdx.x * blockDim.x + threadIdx.x;
    if (i < n) {
        mmax[i] = 0x007FFFFFu;   // fmap(-inf)
        denom[i] = 0.0f;
    }
}

// Per (relation, dim): quaternion (w, ux, uy, uz). Exact reference math.
__global__ void build_quat(const float* __restrict__ rel, float4* __restrict__ quat, int nrel) {
    int i = blockIdx.x * blockDim.x + threadIdx.x;
    if (i >= nrel * HID) return;
    int r = i >> 6, j = i & 63;
    const float* base = rel + (size_t)r * 4 * HID;
    float rx = base[j];
    float ry = base[HID + j];
    float rz = base[2 * HID + j];
    float th = base[3 * HID + j];
    float theta = th * PI_F;            // theta / (EMB_RANGE / PI), EMB_RANGE = 1
    float sn = sinf(theta);
    float w  = cosf(theta);
    float tx = sn * rx, ty = sn * ry, tz = sn * rz;
    float norm = sqrtf(tx * tx + ty * ty + tz * tz);
    float inv = 1.0f / fmaxf(norm, 1e-12f);
    float s = sqrtf(fmaxf(1.0f - w * w, 0.0f));
    quat[i] = make_float4(w, s * tx * inv, s * ty * inv, s * tz * inv);
}

// One wave64 per edge; lane = feature dim. alpha = dot(ent[tail], qv[:192]) / 16.
__global__ void edge_alpha(const float* __restrict__ ent,
                           const float4* __restrict__ quat,
                           const int* __restrict__ eidx, int E,
                           float* __restrict__ alpha,
                           unsigned* __restrict__ mmax) {
    int e = blockIdx.x * (blockDim.x >> 6) + (threadIdx.x >> 6);
    int lane = threadIdx.x & 63;
    if (e >= E) return;
    int h = eidx[e];
    int r = eidx[E + e];
    int t = eidx[2 * E + e];

    const float* eh = ent + (size_t)h * (3 * HID);
    float ex = eh[lane], ey = eh[HID + lane], ez = eh[2 * HID + lane];
    float4 q = quat[r * HID + lane];   // (w, ux, uy, uz)
    float qx = q.x * ex + q.z * ez - q.w * ey;
    float qy = q.x * ey + q.w * ex - q.y * ez;
    float qz = q.x * ez + q.y * ey - q.z * ex;

    const float* et = ent + (size_t)t * (3 * HID);
    float p = et[lane] * qx + et[HID + lane] * qy + et[2 * HID + lane] * qz;

    #pragma unroll
    for (int m = 32; m >= 1; m >>= 1) p += __shfl_xor(p, m, 64);

    if (lane == 0) {
        float a = p * 0.0625f;         // / sqrt(256)
        alpha[e] = a;
        atomicMax(mmax + t, fmap(a));
    }
}

__global__ void edge_exp(const int* __restrict__ eidx, int E,
                         const unsigned* __restrict__ mmax,
                         float* __restrict__ alpha,
                         float* __restrict__ denom) {
    int e = blockIdx.x * blockDim.x + threadIdx.x;
    if (e >= E) return;
    int t = eidx[2 * E + e];
    float m = funmap(mmax[t]);
    float ee = expf(alpha[e] - m);
    alpha[e] = ee;                     // overwrite alpha with exp value
    atomicAdd(denom + t, ee);
}

// One wave64 per edge: recompute qv, scale by attn, scatter-add into out[tail].
__global__ void edge_scatter(const float* __restrict__ ent,
                             const float4* __restrict__ quat,
                             const int* __restrict__ eidx, int E,
                             const float* __restrict__ ealpha,
                             const float* __restrict__ denom,
                             float* __restrict__ out) {
    int e = blockIdx.x * (blockDim.x >> 6) + (threadIdx.x >> 6);
    int lane = threadIdx.x & 63;
    if (e >= E) return;
    int h = eidx[e];
    int r = eidx[E + e];
    int t = eidx[2 * E + e];

    const float* eh = ent + (size_t)h * (3 * HID);
    float ex = eh[lane], ey = eh[HID + lane], ez = eh[2 * HID + lane];
    float4 q = quat[r * HID + lane];
    float qx = q.x * ex + q.z * ez - q.w * ey;
    float qy = q.x * ey + q.w * ex - q.y * ez;
    float qz = q.x * ez + q.y * ey - q.z * ex;
    float qw = -(q.y * ex + q.z * ey + q.w * ez);

    float attn = ealpha[e] / denom[t];

    float* o = out + (size_t)t * (4 * HID);
    atomicAdd(o + lane,            qx * attn);
    atomicAdd(o + HID + lane,      qy * attn);
    atomicAdd(o + 2 * HID + lane,  qz * attn);
    atomicAdd(o + 3 * HID + lane,  qw * attn);
}

extern "C" void kernel_launch(void* const* d_in, const int* in_sizes, int n_in,
                              void* d_out, int out_size, void* d_ws, size_t ws_size,
                              hipStream_t stream) {
    const float* ent  = (const float*)d_in[0];
    const float* rel  = (const float*)d_in[1];
    const int*   eidx = (const int*)d_in[2];
    float* out = (float*)d_out;

    const int n_ent = in_sizes[0] / (3 * HID);
    const int n_rel = in_sizes[1] / (4 * HID);
    const int E     = in_sizes[2] / 3;

    // Workspace layout
    float*    alpha = (float*)d_ws;                 // E floats
    unsigned* mmax  = (unsigned*)(alpha + E);       // n_ent
    float*    denom = (float*)(mmax + n_ent);       // n_ent
    uintptr_t p = (uintptr_t)(denom + n_ent);
    p = (p + 15) & ~(uintptr_t)15;
    float4*   quat  = (float4*)p;                   // n_rel * HID float4s

    hipMemsetAsync(d_out, 0, (size_t)out_size * sizeof(float), stream);

    init_nodes<<<(n_ent + 255) / 256, 256, 0, stream>>>(mmax, denom, n_ent);
    build_quat<<<(n_rel * HID + 255) / 256, 256, 0, stream>>>(rel, quat, n_rel);

    const int waves_per_block = 4;                  // 256 threads
    const int eblocks = (E + waves_per_block - 1) / waves_per_block;

    edge_alpha<<<eblocks, 256, 0, stream>>>(ent, quat, eidx, E, alpha, mmax);
    edge_exp<<<(E + 255) / 256, 256, 0, stream>>>(eidx, E, mmax, alpha, denom);
    edge_scatter<<<eblocks, 256, 0, stream>>>(ent, quat, eidx, E, alpha, denom, out);
}

// Round 2
// 260.261 us; speedup vs baseline: 2.1375x; 2.1375x over previous
//
#include <hip/hip_runtime.h>
#include <stdint.h>
#include <math.h>

#define HID 64
#define PI_F 3.14159262358979330f

// ---------- quaternion table: per (relation, dim) ----------
__global__ void build_quat(const float* __restrict__ rel, float4* __restrict__ quat, int nrel) {
    int i = blockIdx.x * blockDim.x + threadIdx.x;
    if (i >= nrel * HID) return;
    int r = i >> 6, j = i & 63;
    const float* base = rel + (size_t)r * 4 * HID;
    float rx = base[j];
    float ry = base[HID + j];
    float rz = base[2 * HID + j];
    float th = base[3 * HID + j];
    float theta = th * PI_F;            // theta / (EMB_RANGE/PI), EMB_RANGE = 1
    float sn = sinf(theta);
    float w  = cosf(theta);
    float tx = sn * rx, ty = sn * ry, tz = sn * rz;
    float norm = sqrtf(tx * tx + ty * ty + tz * tz);
    float inv = 1.0f / fmaxf(norm, 1e-12f);
    float s = sqrtf(fmaxf(1.0f - w * w, 0.0f));
    quat[i] = make_float4(w, s * tx * inv, s * ty * inv, s * tz * inv);
}

// ---------- counting sort of edges by tail ----------
__global__ void hist_tails(const int* __restrict__ eidx, int E, int* __restrict__ hist) {
    int e = blockIdx.x * blockDim.x + threadIdx.x;
    if (e >= E) return;
    atomicAdd(hist + eidx[2 * E + e], 1);
}

// Single-block exclusive scan of hist[n] -> base[n]. 1024 threads, chunked.
__global__ void scan_hist(const int* __restrict__ hist, int* __restrict__ base, int n) {
    __shared__ int sums[1024];
    const int tid = threadIdx.x;
    const int chunk = (n + 1023) >> 10;
    const int start = tid * chunk;
    const int end = min(start + chunk, n);
    int s = 0;
    for (int i = start; i < end; ++i) s += hist[i];
    sums[tid] = s;
    __syncthreads();
    int v = s;
    for (int off = 1; off < 1024; off <<= 1) {
        int other = (tid >= off) ? sums[tid - off] : 0;
        __syncthreads();
        v += other;
        sums[tid] = v;
        __syncthreads();
    }
    int run = v - s;                      // exclusive prefix of this chunk
    for (int i = start; i < end; ++i) { base[i] = run; run += hist[i]; }
}

__global__ void scatter_order(const int* __restrict__ eidx, int E,
                              const int* __restrict__ base, int* __restrict__ cursor,
                              int* __restrict__ order) {
    int e = blockIdx.x * blockDim.x + threadIdx.x;
    if (e >= E) return;
    int t = eidx[2 * E + e];
    int pos = base[t] + atomicAdd(cursor + t, 1);
    order[pos] = e;
}

// ---------- fused per-tail segment pass: online softmax + weighted sum ----------
__global__ void seg_reduce(const float* __restrict__ ent,
                           const float4* __restrict__ quat,
                           const int* __restrict__ eidx,
                           const int* __restrict__ order,
                           const int* __restrict__ base,
                           const int* __restrict__ hist,
                           int E, int n_ent,
                           float* __restrict__ out) {
    int t = blockIdx.x * (blockDim.x >> 6) + (threadIdx.x >> 6);
    int lane = threadIdx.x & 63;
    if (t >= n_ent) return;
    int deg = hist[t];
    if (deg == 0) return;                 // out row already zeroed
    int start = base[t];

    const float* et = ent + (size_t)t * (3 * HID);
    float kx = et[lane], ky = et[HID + lane], kz = et[2 * HID + lane];

    float m = -INFINITY, denom = 0.0f;
    float ax = 0.0f, ay = 0.0f, az = 0.0f, aw = 0.0f;

    for (int k = 0; k < deg; ++k) {
        int e = order[start + k];
        int h = eidx[e];
        int r = eidx[E + e];
        const float* eh = ent + (size_t)h * (3 * HID);
        float ex = eh[lane], ey = eh[HID + lane], ez = eh[2 * HID + lane];
        float4 q = quat[r * HID + lane];  // (w, ux, uy, uz)
        float qx = q.x * ex + q.z * ez - q.w * ey;
        float qy = q.x * ey + q.w * ex - q.y * ez;
        float qz = q.x * ez + q.y * ey - q.z * ex;
        float qw = -(q.y * ex + q.z * ey + q.w * ez);

        float p = kx * qx + ky * qy + kz * qz;
        #pragma unroll
        for (int s2 = 32; s2 >= 1; s2 >>= 1) p += __shfl_xor(p, s2, 64);
        float alpha = p * 0.0625f;        // / sqrt(256)

        float mnew = fmaxf(m, alpha);
        float c  = __expf(m - mnew);      // first iter: exp(-inf)=0
        float pe = __expf(alpha - mnew);
        denom = denom * c + pe;
        ax = ax * c + pe * qx;
        ay = ay * c + pe * qy;
        az = az * c + pe * qz;
        aw = aw * c + pe * qw;
        m = mnew;
    }

    float inv = 1.0f / denom;
    float* o = out + (size_t)t * (4 * HID);
    o[lane]            = ax * inv;
    o[HID + lane]      = ay * inv;
    o[2 * HID + lane]  = az * inv;
    o[3 * HID + lane]  = aw * inv;
}

extern "C" void kernel_launch(void* const* d_in, const int* in_sizes, int n_in,
                              void* d_out, int out_size, void* d_ws, size_t ws_size,
                              hipStream_t stream) {
    const float* ent  = (const float*)d_in[0];
    const float* rel  = (const float*)d_in[1];
    const int*   eidx = (const int*)d_in[2];
    float* out = (float*)d_out;

    const int n_ent = in_sizes[0] / (3 * HID);
    const int n_rel = in_sizes[1] / (4 * HID);
    const int E     = in_sizes[2] / 3;

    // Workspace layout
    int* order  = (int*)d_ws;                       // E
    int* hist   = order + E;                        // n_ent
    int* base   = hist + n_ent;                     // n_ent
    int* cursor = base + n_ent;                     // n_ent
    uintptr_t p = (uintptr_t)(cursor + n_ent);
    p = (p + 15) & ~(uintptr_t)15;
    float4* quat = (float4*)p;                      // n_rel * HID

    hipMemsetAsync(d_out, 0, (size_t)out_size * sizeof(float), stream);
    hipMemsetAsync(hist, 0, (size_t)n_ent * sizeof(int), stream);
    hipMemsetAsync(cursor, 0, (size_t)n_ent * sizeof(int), stream);

    build_quat<<<(n_rel * HID + 255) / 256, 256, 0, stream>>>(rel, quat, n_rel);
    hist_tails<<<(E + 255) / 256, 256, 0, stream>>>(eidx, E, hist);
    scan_hist<<<1, 1024, 0, stream>>>(hist, base, n_ent);
    scatter_order<<<(E + 255) / 256, 256, 0, stream>>>(eidx, E, base, cursor, order);

    const int waves_per_block = 4;                  // 256 threads
    const int tblocks = (n_ent + waves_per_block - 1) / waves_per_block;
    seg_reduce<<<tblocks, 256, 0, stream>>>(ent, quat, eidx, order, base, hist, E, n_ent, out);
}

// Round 3
// 208.619 us; speedup vs baseline: 2.6666x; 1.2475x over previous
//
#include <hip/hip_runtime.h>
#include <stdint.h>
#include <math.h>

#define HID 64
#define PI_F 3.14159262358979330f

// ---------- fused prep: quaternion table + tail histogram ----------
__global__ void prep(const float* __restrict__ rel, float4* __restrict__ quat, int nrel,
                     const int* __restrict__ eidx, int E, int* __restrict__ hist,
                     int qblocks) {
    if ((int)blockIdx.x < qblocks) {
        int i = blockIdx.x * blockDim.x + threadIdx.x;
        if (i >= nrel * HID) return;
        int r = i >> 6, j = i & 63;
        const float* base = rel + (size_t)r * 4 * HID;
        float rx = base[j];
        float ry = base[HID + j];
        float rz = base[2 * HID + j];
        float th = base[3 * HID + j];
        float theta = th * PI_F;
        float sn = sinf(theta);
        float w  = cosf(theta);
        float tx = sn * rx, ty = sn * ry, tz = sn * rz;
        float norm = sqrtf(tx * tx + ty * ty + tz * tz);
        float inv = 1.0f / fmaxf(norm, 1e-12f);
        float s = sqrtf(fmaxf(1.0f - w * w, 0.0f));
        quat[i] = make_float4(w, s * tx * inv, s * ty * inv, s * tz * inv);
    } else {
        int e = (blockIdx.x - qblocks) * blockDim.x + threadIdx.x;
        if (e >= E) return;
        atomicAdd(hist + eidx[2 * E + e], 1);
    }
}

// Single-block exclusive scan of hist[n] -> base[n], base[n]=E sentinel.
__global__ void scan_hist(const int* __restrict__ hist, int* __restrict__ base, int n, int E) {
    __shared__ int sums[1024];
    const int tid = threadIdx.x;
    const int chunk = (n + 1023) >> 10;
    const int start = tid * chunk;
    const int end = min(start + chunk, n);
    int s = 0;
    for (int i = start; i < end; ++i) s += hist[i];
    sums[tid] = s;
    __syncthreads();
    int v = s;
    for (int off = 1; off < 1024; off <<= 1) {
        int other = (tid >= off) ? sums[tid - off] : 0;
        __syncthreads();
        v += other;
        sums[tid] = v;
        __syncthreads();
    }
    int run = v - s;                      // exclusive prefix of this chunk
    for (int i = start; i < end; ++i) { base[i] = run; run += hist[i]; }
    if (tid == 1023) base[n] = E;
}

// Scatter packed (head, rel) records into tail-sorted position.
__global__ void scatter_hr(const int* __restrict__ eidx, int E,
                           const int* __restrict__ base, int* __restrict__ cursor,
                           int2* __restrict__ hr) {
    int e = blockIdx.x * blockDim.x + threadIdx.x;
    if (e >= E) return;
    int t = eidx[2 * E + e];
    int pos = base[t] + atomicAdd(cursor + t, 1);
    hr[pos] = make_int2(eidx[e], eidx[E + e]);
}

// ---------- fused per-tail pass: online softmax + weighted sum, 2-way ILP ----------
__global__ void seg_reduce(const float* __restrict__ ent,
                           const float4* __restrict__ quat,
                           const int2* __restrict__ hr,
                           const int* __restrict__ base,
                           int n_ent,
                           float* __restrict__ out) {
    int t = blockIdx.x * (blockDim.x >> 6) + (threadIdx.x >> 6);
    int lane = threadIdx.x & 63;
    if (t >= n_ent) return;
    int start = base[t];
    int end   = base[t + 1];

    float* o = out + (size_t)t * (4 * HID);
    if (start == end) {                   // empty segment -> zeros
        o[lane] = 0.0f; o[HID + lane] = 0.0f;
        o[2 * HID + lane] = 0.0f; o[3 * HID + lane] = 0.0f;
        return;
    }

    const float* et = ent + (size_t)t * (3 * HID);
    float kx = et[lane], ky = et[HID + lane], kz = et[2 * HID + lane];

    // Two independent online-softmax states (even/odd edges)
    float m1 = -INFINITY, d1 = 0.0f, ax1 = 0, ay1 = 0, az1 = 0, aw1 = 0;
    float m2 = -INFINITY, d2 = 0.0f, ax2 = 0, ay2 = 0, az2 = 0, aw2 = 0;

    int k = start;
    for (; k + 1 < end; k += 2) {
        int2 e1 = hr[k], e2 = hr[k + 1];
        const float* h1 = ent + (size_t)e1.x * (3 * HID);
        const float* h2 = ent + (size_t)e2.x * (3 * HID);
        float ex1 = h1[lane], ey1 = h1[HID + lane], ez1 = h1[2 * HID + lane];
        float ex2 = h2[lane], ey2 = h2[HID + lane], ez2 = h2[2 * HID + lane];
        float4 q1 = quat[e1.y * HID + lane];
        float4 q2 = quat[e2.y * HID + lane];

        float qx1 = q1.x * ex1 + q1.z * ez1 - q1.w * ey1;
        float qy1 = q1.x * ey1 + q1.w * ex1 - q1.y * ez1;
        float qz1 = q1.x * ez1 + q1.y * ey1 - q1.z * ex1;
        float qw1 = -(q1.y * ex1 + q1.z * ey1 + q1.w * ez1);
        float qx2 = q2.x * ex2 + q2.z * ez2 - q2.w * ey2;
        float qy2 = q2.x * ey2 + q2.w * ex2 - q2.y * ez2;
        float qz2 = q2.x * ez2 + q2.y * ey2 - q2.z * ex2;
        float qw2 = -(q2.y * ex2 + q2.z * ey2 + q2.w * ez2);

        float p1 = kx * qx1 + ky * qy1 + kz * qz1;
        float p2 = kx * qx2 + ky * qy2 + kz * qz2;
        #pragma unroll
        for (int s2 = 32; s2 >= 1; s2 >>= 1) {
            p1 += __shfl_xor(p1, s2, 64);
            p2 += __shfl_xor(p2, s2, 64);
        }
        float a1 = p1 * 0.0625f;
        float a2 = p2 * 0.0625f;

        float mn1 = fmaxf(m1, a1);
        float c1  = __expf(m1 - mn1);
        float pe1 = __expf(a1 - mn1);
        d1 = d1 * c1 + pe1;
        ax1 = ax1 * c1 + pe1 * qx1;
        ay1 = ay1 * c1 + pe1 * qy1;
        az1 = az1 * c1 + pe1 * qz1;
        aw1 = aw1 * c1 + pe1 * qw1;
        m1 = mn1;

        float mn2 = fmaxf(m2, a2);
        float c2  = __expf(m2 - mn2);
        float pe2 = __expf(a2 - mn2);
        d2 = d2 * c2 + pe2;
        ax2 = ax2 * c2 + pe2 * qx2;
        ay2 = ay2 * c2 + pe2 * qy2;
        az2 = az2 * c2 + pe2 * qz2;
        aw2 = aw2 * c2 + pe2 * qw2;
        m2 = mn2;
    }
    if (k < end) {                        // leftover edge -> state 1
        int2 e1 = hr[k];
        const float* h1 = ent + (size_t)e1.x * (3 * HID);
        float ex1 = h1[lane], ey1 = h1[HID + lane], ez1 = h1[2 * HID + lane];
        float4 q1 = quat[e1.y * HID + lane];
        float qx1 = q1.x * ex1 + q1.z * ez1 - q1.w * ey1;
        float qy1 = q1.x * ey1 + q1.w * ex1 - q1.y * ez1;
        float qz1 = q1.x * ez1 + q1.y * ey1 - q1.z * ex1;
        float qw1 = -(q1.y * ex1 + q1.z * ey1 + q1.w * ez1);
        float p1 = kx * qx1 + ky * qy1 + kz * qz1;
        #pragma unroll
        for (int s2 = 32; s2 >= 1; s2 >>= 1) p1 += __shfl_xor(p1, s2, 64);
        float a1 = p1 * 0.0625f;
        float mn1 = fmaxf(m1, a1);
        float c1  = __expf(m1 - mn1);
        float pe1 = __expf(a1 - mn1);
        d1 = d1 * c1 + pe1;
        ax1 = ax1 * c1 + pe1 * qx1;
        ay1 = ay1 * c1 + pe1 * qy1;
        az1 = az1 * c1 + pe1 * qz1;
        aw1 = aw1 * c1 + pe1 * qw1;
        m1 = mn1;
    }

    // Merge the two states
    float m = fmaxf(m1, m2);
    float c1 = __expf(m1 - m), c2 = __expf(m2 - m);
    float d = d1 * c1 + d2 * c2;
    float inv = (d > 0.0f) ? 1.0f / d : 0.0f;
    o[lane]           = (ax1 * c1 + ax2 * c2) * inv;
    o[HID + lane]     = (ay1 * c1 + ay2 * c2) * inv;
    o[2 * HID + lane] = (az1 * c1 + az2 * c2) * inv;
    o[3 * HID + lane] = (aw1 * c1 + aw2 * c2) * inv;
}

extern "C" void kernel_launch(void* const* d_in, const int* in_sizes, int n_in,
                              void* d_out, int out_size, void* d_ws, size_t ws_size,
                              hipStream_t stream) {
    const float* ent  = (const float*)d_in[0];
    const float* rel  = (const float*)d_in[1];
    const int*   eidx = (const int*)d_in[2];
    float* out = (float*)d_out;

    const int n_ent = in_sizes[0] / (3 * HID);
    const int n_rel = in_sizes[1] / (4 * HID);
    const int E     = in_sizes[2] / 3;

    // Workspace layout
    int2* hr    = (int2*)d_ws;                      // E int2 (8B each)
    int*  hist  = (int*)(hr + E);                   // n_ent
    int*  base  = hist + n_ent;                     // n_ent + 1
    int*  cursor= base + n_ent + 1;                 // n_ent
    uintptr_t p = (uintptr_t)(cursor + n_ent);
    p = (p + 15) & ~(uintptr_t)15;
    float4* quat = (float4*)p;                      // n_rel * HID

    // one memset zeroes hist + base + cursor (contiguous)
    hipMemsetAsync(hist, 0, (size_t)(3 * n_ent + 1) * sizeof(int), stream);

    const int qblocks = (n_rel * HID + 255) / 256;
    const int eblocks1 = (E + 255) / 256;
    prep<<<qblocks + eblocks1, 256, 0, stream>>>(rel, quat, n_rel, eidx, E, hist, qblocks);
    scan_hist<<<1, 1024, 0, stream>>>(hist, base, n_ent, E);
    scatter_hr<<<eblocks1, 256, 0, stream>>>(eidx, E, base, cursor, hr);

    const int waves_per_block = 4;                  // 256 threads
    const int tblocks = (n_ent + waves_per_block - 1) / waves_per_block;
    seg_reduce<<<tblocks, 256, 0, stream>>>(ent, quat, hr, base, n_ent, out);
}

// Round 4
// 166.988 us; speedup vs baseline: 3.3314x; 1.2493x over previous
//
#include <hip/hip_runtime.h>
#include <stdint.h>
#include <math.h>

#define HID 64
#define PI_F 3.14159262358979330f

// ---------- fused prep: quaternion table + tail histogram ----------
__global__ void prep(const float* __restrict__ rel, float4* __restrict__ quat, int nrel,
                     const int* __restrict__ eidx, int E, int* __restrict__ hist,
                     int qblocks) {
    if ((int)blockIdx.x < qblocks) {
        int i = blockIdx.x * blockDim.x + threadIdx.x;
        if (i >= nrel * HID) return;
        int r = i >> 6, j = i & 63;
        const float* base = rel + (size_t)r * 4 * HID;
        float rx = base[j];
        float ry = base[HID + j];
        float rz = base[2 * HID + j];
        float th = base[3 * HID + j];
        float theta = th * PI_F;
        float sn = sinf(theta);
        float w  = cosf(theta);
        float tx = sn * rx, ty = sn * ry, tz = sn * rz;
        float norm = sqrtf(tx * tx + ty * ty + tz * tz);
        float inv = 1.0f / fmaxf(norm, 1e-12f);
        float s = sqrtf(fmaxf(1.0f - w * w, 0.0f));
        quat[i] = make_float4(w, s * tx * inv, s * ty * inv, s * tz * inv);
    } else {
        int e = (blockIdx.x - qblocks) * blockDim.x + threadIdx.x;
        if (e >= E) return;
        atomicAdd(hist + eidx[2 * E + e], 1);
    }
}

// ---------- 3-level parallel exclusive scan of hist -> base ----------
__global__ void scan1(const int* __restrict__ hist, int* __restrict__ base,
                      int* __restrict__ partial, int n) {
    __shared__ int buf[256];
    int tid = threadIdx.x;
    int gid = blockIdx.x * 256 + tid;
    int v = (gid < n) ? hist[gid] : 0;
    buf[tid] = v;
    __syncthreads();
    #pragma unroll
    for (int off = 1; off < 256; off <<= 1) {
        int x = (tid >= off) ? buf[tid - off] : 0;
        __syncthreads();
        buf[tid] += x;
        __syncthreads();
    }
    if (gid < n) base[gid] = buf[tid] - v;        // exclusive within block
    if (tid == 255) partial[blockIdx.x] = buf[255];
}

__global__ void scan2(int* __restrict__ partial, int nb) {   // nb <= 256, 1 block
    __shared__ int buf[256];
    int tid = threadIdx.x;
    int v = (tid < nb) ? partial[tid] : 0;
    buf[tid] = v;
    __syncthreads();
    #pragma unroll
    for (int off = 1; off < 256; off <<= 1) {
        int x = (tid >= off) ? buf[tid - off] : 0;
        __syncthreads();
        buf[tid] += x;
        __syncthreads();
    }
    if (tid < nb) partial[tid] = buf[tid] - v;    // exclusive
}

__global__ void scan3(int* __restrict__ base, const int* __restrict__ partial,
                      int n, int E) {
    int gid = blockIdx.x * 256 + threadIdx.x;
    if (gid < n) base[gid] += partial[blockIdx.x];
    else if (gid == n) base[n] = E;               // sentinel
}

// ---------- scatter packed (head, rel) into tail-sorted position ----------
__global__ void scatter_hr(const int* __restrict__ eidx, int E,
                           const int* __restrict__ base, int* __restrict__ cursor,
                           int2* __restrict__ hr) {
    int e = blockIdx.x * blockDim.x + threadIdx.x;
    if (e >= E) return;
    int t = eidx[2 * E + e];
    int pos = base[t] + atomicAdd(cursor + t, 1);
    hr[pos] = make_int2(eidx[e], eidx[E + e]);
}

// ---------- fused per-tail pass: online softmax + weighted sum, 4-way ILP ----------
__global__ void seg_reduce(const float* __restrict__ ent,
                           const float4* __restrict__ quat,
                           const int2* __restrict__ hr,
                           const int* __restrict__ base,
                           int n_ent,
                           float* __restrict__ out) {
    int t = blockIdx.x * (blockDim.x >> 6) + (threadIdx.x >> 6);
    int lane = threadIdx.x & 63;
    if (t >= n_ent) return;
    int start = base[t];
    int end   = base[t + 1];

    float* o = out + (size_t)t * (4 * HID);
    if (start == end) {                   // empty segment -> zeros
        o[lane] = 0.0f; o[HID + lane] = 0.0f;
        o[2 * HID + lane] = 0.0f; o[3 * HID + lane] = 0.0f;
        return;
    }

    const float* et = ent + (size_t)t * (3 * HID);
    float kx = et[lane], ky = et[HID + lane], kz = et[2 * HID + lane];

    float m[4], d[4], ax[4], ay[4], az[4], aw[4];
    #pragma unroll
    for (int i = 0; i < 4; ++i) {
        m[i] = -INFINITY; d[i] = 0.0f;
        ax[i] = 0.0f; ay[i] = 0.0f; az[i] = 0.0f; aw[i] = 0.0f;
    }

    int k = start;
    for (; k + 3 < end; k += 4) {
        int2 e[4];
        #pragma unroll
        for (int i = 0; i < 4; ++i) e[i] = hr[k + i];
        float ex[4], ey[4], ez[4]; float4 q[4];
        #pragma unroll
        for (int i = 0; i < 4; ++i) {
            const float* h = ent + (size_t)e[i].x * (3 * HID);
            ex[i] = h[lane]; ey[i] = h[HID + lane]; ez[i] = h[2 * HID + lane];
            q[i] = quat[e[i].y * HID + lane];
        }
        float qx[4], qy[4], qz[4], qw[4], p[4];
        #pragma unroll
        for (int i = 0; i < 4; ++i) {
            qx[i] = q[i].x * ex[i] + q[i].z * ez[i] - q[i].w * ey[i];
            qy[i] = q[i].x * ey[i] + q[i].w * ex[i] - q[i].y * ez[i];
            qz[i] = q[i].x * ez[i] + q[i].y * ey[i] - q[i].z * ex[i];
            qw[i] = -(q[i].y * ex[i] + q[i].z * ey[i] + q[i].w * ez[i]);
            p[i] = kx * qx[i] + ky * qy[i] + kz * qz[i];
        }
        #pragma unroll
        for (int s2 = 32; s2 >= 1; s2 >>= 1) {
            #pragma unroll
            for (int i = 0; i < 4; ++i) p[i] += __shfl_xor(p[i], s2, 64);
        }
        #pragma unroll
        for (int i = 0; i < 4; ++i) {
            float a = p[i] * 0.0625f;
            float mn = fmaxf(m[i], a);
            float c  = __expf(m[i] - mn);
            float pe = __expf(a - mn);
            d[i] = d[i] * c + pe;
            ax[i] = ax[i] * c + pe * qx[i];
            ay[i] = ay[i] * c + pe * qy[i];
            az[i] = az[i] * c + pe * qz[i];
            aw[i] = aw[i] * c + pe * qw[i];
            m[i] = mn;
        }
    }
    for (; k < end; ++k) {                // remainder -> state 0
        int2 e0 = hr[k];
        const float* h = ent + (size_t)e0.x * (3 * HID);
        float ex0 = h[lane], ey0 = h[HID + lane], ez0 = h[2 * HID + lane];
        float4 q0 = quat[e0.y * HID + lane];
        float qx0 = q0.x * ex0 + q0.z * ez0 - q0.w * ey0;
        float qy0 = q0.x * ey0 + q0.w * ex0 - q0.y * ez0;
        float qz0 = q0.x * ez0 + q0.y * ey0 - q0.z * ex0;
        float qw0 = -(q0.y * ex0 + q0.z * ey0 + q0.w * ez0);
        float p0 = kx * qx0 + ky * qy0 + kz * qz0;
        #pragma unroll
        for (int s2 = 32; s2 >= 1; s2 >>= 1) p0 += __shfl_xor(p0, s2, 64);
        float a = p0 * 0.0625f;
        float mn = fmaxf(m[0], a);
        float c  = __expf(m[0] - mn);
        float pe = __expf(a - mn);
        d[0] = d[0] * c + pe;
        ax[0] = ax[0] * c + pe * qx0;
        ay[0] = ay[0] * c + pe * qy0;
        az[0] = az[0] * c + pe * qz0;
        aw[0] = aw[0] * c + pe * qw0;
        m[0] = mn;
    }

    // merge 4 states (empty states: exp(-inf - m) = 0)
    float mm = fmaxf(fmaxf(m[0], m[1]), fmaxf(m[2], m[3]));
    float dd = 0.0f, rx = 0.0f, ry = 0.0f, rz = 0.0f, rw = 0.0f;
    #pragma unroll
    for (int i = 0; i < 4; ++i) {
        float c = __expf(m[i] - mm);
        dd += d[i] * c;
        rx += ax[i] * c; ry += ay[i] * c; rz += az[i] * c; rw += aw[i] * c;
    }
    float inv = (dd > 0.0f) ? 1.0f / dd : 0.0f;
    o[lane]           = rx * inv;
    o[HID + lane]     = ry * inv;
    o[2 * HID + lane] = rz * inv;
    o[3 * HID + lane] = rw * inv;
}

extern "C" void kernel_launch(void* const* d_in, const int* in_sizes, int n_in,
                              void* d_out, int out_size, void* d_ws, size_t ws_size,
                              hipStream_t stream) {
    const float* ent  = (const float*)d_in[0];
    const float* rel  = (const float*)d_in[1];
    const int*   eidx = (const int*)d_in[2];
    float* out = (float*)d_out;

    const int n_ent = in_sizes[0] / (3 * HID);
    const int n_rel = in_sizes[1] / (4 * HID);
    const int E     = in_sizes[2] / 3;

    // Workspace layout
    int2* hr     = (int2*)d_ws;                     // E int2
    int*  hist   = (int*)(hr + E);                  // n_ent
    int*  base   = hist + n_ent;                    // n_ent + 1
    int*  cursor = base + n_ent + 1;                // n_ent
    int*  partial= cursor + n_ent;                  // <=256
    uintptr_t p = (uintptr_t)(partial + 256);
    p = (p + 15) & ~(uintptr_t)15;
    float4* quat = (float4*)p;                      // n_rel * HID

    // zero hist + base + cursor (contiguous)
    hipMemsetAsync(hist, 0, (size_t)(3 * n_ent + 1) * sizeof(int), stream);

    const int qblocks  = (n_rel * HID + 255) / 256;
    const int eblocks1 = (E + 255) / 256;
    prep<<<qblocks + eblocks1, 256, 0, stream>>>(rel, quat, n_rel, eidx, E, hist, qblocks);

    const int nb = (n_ent + 255) / 256;             // 196 for n_ent=50000 (<=256)
    scan1<<<nb, 256, 0, stream>>>(hist, base, partial, n_ent);
    scan2<<<1, 256, 0, stream>>>(partial, nb);
    scan3<<<(n_ent + 1 + 255) / 256, 256, 0, stream>>>(base, partial, n_ent, E);

    scatter_hr<<<eblocks1, 256, 0, stream>>>(eidx, E, base, cursor, hr);

    const int waves_per_block = 4;                  // 256 threads
    const int tblocks = (n_ent + waves_per_block - 1) / waves_per_block;
    seg_reduce<<<tblocks, 256, 0, stream>>>(ent, quat, hr, base, n_ent, out);
}

// Round 5
// 141.055 us; speedup vs baseline: 3.9439x; 1.1838x over previous
//
#include <hip/hip_runtime.h>
#include <stdint.h>
#include <math.h>

#define HID 64
#define PI_F 3.14159262358979330f

// ---------- fused prep: quaternion table + tail histogram ----------
__global__ void prep(const float* __restrict__ rel, float4* __restrict__ quat, int nrel,
                     const int* __restrict__ eidx, int E, int* __restrict__ hist,
                     int qblocks) {
    if ((int)blockIdx.x < qblocks) {
        int i = blockIdx.x * blockDim.x + threadIdx.x;
        if (i >= nrel * HID) return;
        int r = i >> 6, j = i & 63;
        const float* base = rel + (size_t)r * 4 * HID;
        float rx = base[j];
        float ry = base[HID + j];
        float rz = base[2 * HID + j];
        float th = base[3 * HID + j];
        float theta = th * PI_F;
        float sn = sinf(theta);
        float w  = cosf(theta);
        float tx = sn * rx, ty = sn * ry, tz = sn * rz;
        float norm = sqrtf(tx * tx + ty * ty + tz * tz);
        float inv = 1.0f / fmaxf(norm, 1e-12f);
        float s = sqrtf(fmaxf(1.0f - w * w, 0.0f));
        quat[i] = make_float4(w, s * tx * inv, s * ty * inv, s * tz * inv);
    } else {
        int e = (blockIdx.x - qblocks) * blockDim.x + threadIdx.x;
        if (e >= E) return;
        atomicAdd(hist + eidx[2 * E + e], 1);
    }
}

// ---------- parallel exclusive scan of hist -> base (2 dispatches) ----------
__global__ void scan1(const int* __restrict__ hist, int* __restrict__ base,
                      int* __restrict__ partial, int n) {
    __shared__ int buf[256];
    int tid = threadIdx.x;
    int gid = blockIdx.x * 256 + tid;
    int v = (gid < n) ? hist[gid] : 0;
    buf[tid] = v;
    __syncthreads();
    #pragma unroll
    for (int off = 1; off < 256; off <<= 1) {
        int x = (tid >= off) ? buf[tid - off] : 0;
        __syncthreads();
        buf[tid] += x;
        __syncthreads();
    }
    if (gid < n) base[gid] = buf[tid] - v;        // exclusive within block
    if (tid == 255) partial[blockIdx.x] = buf[255];
}

// Every block redundantly scans the <=256 partials in LDS, applies its offset.
__global__ void scan23(int* __restrict__ base, const int* __restrict__ partial,
                       int nb, int n, int E) {
    __shared__ int buf[256];
    int tid = threadIdx.x;
    int v = (tid < nb) ? partial[tid] : 0;
    buf[tid] = v;
    __syncthreads();
    #pragma unroll
    for (int off = 1; off < 256; off <<= 1) {
        int x = (tid >= off) ? buf[tid - off] : 0;
        __syncthreads();
        buf[tid] += x;
        __syncthreads();
    }
    int bsum = ((int)blockIdx.x < nb) ? partial[blockIdx.x] : 0;
    int boff = buf[blockIdx.x] - bsum;            // exclusive prefix of this block
    int gid = blockIdx.x * 256 + tid;
    if (gid < n) base[gid] += boff;
    else if (gid == n) base[n] = E;               // sentinel
}

// ---------- scatter packed (head, rel) into tail-sorted position ----------
__global__ void scatter_hr(const int* __restrict__ eidx, int E,
                           const int* __restrict__ base, int* __restrict__ cursor,
                           int2* __restrict__ hr) {
    int e = blockIdx.x * blockDim.x + threadIdx.x;
    if (e >= E) return;
    int t = eidx[2 * E + e];
    int pos = base[t] + atomicAdd(cursor + t, 1);
    hr[pos] = make_int2(eidx[e], eidx[E + e]);
}

// ---------- fused per-tail pass: 16 lanes/edge, 4 edges/wave ----------
__global__ void seg_reduce(const float* __restrict__ ent,
                           const float4* __restrict__ quat,
                           const int2* __restrict__ hr,
                           const int* __restrict__ base,
                           int n_ent,
                           float* __restrict__ out) {
    int t = blockIdx.x * (blockDim.x >> 6) + (threadIdx.x >> 6);
    int lane = threadIdx.x & 63;
    if (t >= n_ent) return;
    int sub = lane >> 4;                  // edge slot 0..3
    int j   = lane & 15;                  // dim group: dims 4j..4j+3

    int start = base[t];
    int end   = base[t + 1];

    const float4* krow = (const float4*)(ent + (size_t)t * (3 * HID));
    float4 kx = krow[j], ky = krow[16 + j], kz = krow[32 + j];

    float m = -1e30f, dnm = 0.0f;
    float4 ax = make_float4(0.f, 0.f, 0.f, 0.f);
    float4 ay = ax, az = ax, aw = ax;

    for (int k0 = start; k0 < end; k0 += 4) {
        int e = k0 + sub;
        bool valid = (e < end);
        int ec = valid ? e : (end - 1);
        int2 her = hr[ec];
        const float4* h = (const float4*)(ent + (size_t)her.x * (3 * HID));
        float4 hx = h[j], hy = h[16 + j], hz = h[32 + j];
        const float4* qr = quat + (size_t)her.y * HID + 4 * j;
        float4 q0 = qr[0], q1 = qr[1], q2 = qr[2], q3 = qr[3];

        float4 qx, qy, qz, qw;
        float p = 0.0f;
        #define DO_DIM(F, Q) { \
            float ex = hx.F, ey = hy.F, ez = hz.F; \
            float w = Q.x, ux = Q.y, uy = Q.z, uz = Q.w; \
            float rqx = w * ex + uy * ez - uz * ey; \
            float rqy = w * ey + uz * ex - ux * ez; \
            float rqz = w * ez + ux * ey - uy * ex; \
            float rqw = -(ux * ex + uy * ey + uz * ez); \
            p += kx.F * rqx + ky.F * rqy + kz.F * rqz; \
            qx.F = rqx; qy.F = rqy; qz.F = rqz; qw.F = rqw; }
        DO_DIM(x, q0)
        DO_DIM(y, q1)
        DO_DIM(z, q2)
        DO_DIM(w, q3)
        #undef DO_DIM

        // 4-step reduce within each 16-lane group (shared by 4 edges)
        p += __shfl_xor(p, 1, 64);
        p += __shfl_xor(p, 2, 64);
        p += __shfl_xor(p, 4, 64);
        p += __shfl_xor(p, 8, 64);

        float a  = valid ? (p * 0.0625f) : -1e30f;
        float mn = fmaxf(m, a);
        float c  = __expf(m - mn);        // finite sentinels: never NaN
        float pe = valid ? __expf(a - mn) : 0.0f;
        dnm = dnm * c + pe;
        ax.x = ax.x * c + pe * qx.x; ax.y = ax.y * c + pe * qx.y;
        ax.z = ax.z * c + pe * qx.z; ax.w = ax.w * c + pe * qx.w;
        ay.x = ay.x * c + pe * qy.x; ay.y = ay.y * c + pe * qy.y;
        ay.z = ay.z * c + pe * qy.z; ay.w = ay.w * c + pe * qy.w;
        az.x = az.x * c + pe * qz.x; az.y = az.y * c + pe * qz.y;
        az.z = az.z * c + pe * qz.z; az.w = az.w * c + pe * qz.w;
        aw.x = aw.x * c + pe * qw.x; aw.y = aw.y * c + pe * qw.y;
        aw.z = aw.z * c + pe * qw.z; aw.w = aw.w * c + pe * qw.w;
        m = mn;
    }

    // ---- merge the 4 edge-slot states across subwarps ----
    float mo = fmaxf(m, __shfl_xor(m, 16, 64));
    mo = fmaxf(mo, __shfl_xor(mo, 32, 64));
    float c = __expf(m - mo);             // deg==0: exp(0)=1 on zero accs
    dnm *= c;
    ax.x *= c; ax.y *= c; ax.z *= c; ax.w *= c;
    ay.x *= c; ay.y *= c; ay.z *= c; ay.w *= c;
    az.x *= c; az.y *= c; az.z *= c; az.w *= c;
    aw.x *= c; aw.y *= c; aw.z *= c; aw.w *= c;

    #pragma unroll
    for (int mask = 16; mask <= 32; mask <<= 1) {
        dnm += __shfl_xor(dnm, mask, 64);
        ax.x += __shfl_xor(ax.x, mask, 64); ax.y += __shfl_xor(ax.y, mask, 64);
        ax.z += __shfl_xor(ax.z, mask, 64); ax.w += __shfl_xor(ax.w, mask, 64);
        ay.x += __shfl_xor(ay.x, mask, 64); ay.y += __shfl_xor(ay.y, mask, 64);
        ay.z += __shfl_xor(ay.z, mask, 64); ay.w += __shfl_xor(ay.w, mask, 64);
        az.x += __shfl_xor(az.x, mask, 64); az.y += __shfl_xor(az.y, mask, 64);
        az.z += __shfl_xor(az.z, mask, 64); az.w += __shfl_xor(az.w, mask, 64);
        aw.x += __shfl_xor(aw.x, mask, 64); aw.y += __shfl_xor(aw.y, mask, 64);
        aw.z += __shfl_xor(aw.z, mask, 64); aw.w += __shfl_xor(aw.w, mask, 64);
    }

    float inv = (dnm > 0.0f) ? 1.0f / dnm : 0.0f;
    // lane = sub*16+j writes component `sub`, dims 4j..4j+3
    float4 lo = (sub & 1) ? ay : ax;
    float4 hi = (sub & 1) ? aw : az;
    float4 val = (sub & 2) ? hi : lo;
    val.x *= inv; val.y *= inv; val.z *= inv; val.w *= inv;
    float4* o4 = (float4*)(out + (size_t)t * (4 * HID));
    o4[lane] = val;
}

extern "C" void kernel_launch(void* const* d_in, const int* in_sizes, int n_in,
                              void* d_out, int out_size, void* d_ws, size_t ws_size,
                              hipStream_t stream) {
    const float* ent  = (const float*)d_in[0];
    const float* rel  = (const float*)d_in[1];
    const int*   eidx = (const int*)d_in[2];
    float* out = (float*)d_out;

    const int n_ent = in_sizes[0] / (3 * HID);
    const int n_rel = in_sizes[1] / (4 * HID);
    const int E     = in_sizes[2] / 3;

    // Workspace layout
    int2* hr     = (int2*)d_ws;                     // E int2
    int*  hist   = (int*)(hr + E);                  // n_ent
    int*  base   = hist + n_ent;                    // n_ent + 1
    int*  cursor = base + n_ent + 1;                // n_ent
    int*  partial= cursor + n_ent;                  // <=256
    uintptr_t p = (uintptr_t)(partial + 256);
    p = (p + 15) & ~(uintptr_t)15;
    float4* quat = (float4*)p;                      // n_rel * HID

    // zero hist + base + cursor (contiguous)
    hipMemsetAsync(hist, 0, (size_t)(3 * n_ent + 1) * sizeof(int), stream);

    const int qblocks  = (n_rel * HID + 255) / 256;
    const int eblocks1 = (E + 255) / 256;
    prep<<<qblocks + eblocks1, 256, 0, stream>>>(rel, quat, n_rel, eidx, E, hist, qblocks);

    const int nb = (n_ent + 255) / 256;             // 196 for n_ent=50000 (<=256)
    scan1<<<nb, 256, 0, stream>>>(hist, base, partial, n_ent);
    scan23<<<(n_ent + 1 + 255) / 256, 256, 0, stream>>>(base, partial, nb, n_ent, E);

    scatter_hr<<<eblocks1, 256, 0, stream>>>(eidx, E, base, cursor, hr);

    const int waves_per_block = 4;                  // 256 threads
    const int tblocks = (n_ent + waves_per_block - 1) / waves_per_block;
    seg_reduce<<<tblocks, 256, 0, stream>>>(ent, quat, hr, base, n_ent, out);
}